// Round 6
// baseline (24115.450 us; speedup 1.0000x reference)
//
#include <hip/hip_runtime.h>
#include <hip/hip_fp16.h>

#define BB 64
#define TT 2048
#define DD 256
#define HH 256
#define CHUNK 256
#define NCHUNK 8
#define PB 8          // batches per serial block
#define RS 272        // A-row stride (f16): 544 B -> conflict-free b128 frag reads

typedef _Float16 f16x8 __attribute__((ext_vector_type(8)));
typedef _Float16 f16x4 __attribute__((ext_vector_type(4)));
typedef _Float16 h2t   __attribute__((ext_vector_type(2)));
typedef float    f32x4 __attribute__((ext_vector_type(4)));
union V8 { f16x8 v; h2t p[4]; };

__device__ __forceinline__ float sigm(float v){ return __builtin_amdgcn_rcpf(1.f+__expf(-v)); }
__device__ __forceinline__ float tanh_f(float v){ float e=__expf(2.f*v); return 1.f-2.f*__builtin_amdgcn_rcpf(e+1.f); }

// Pack W [256][1024] f32 (k-major) into f16 layout [k/8][1024][8] (for the GEMM)
__global__ void pack_w(const float* __restrict__ w, _Float16* __restrict__ o) {
    int idx = blockIdx.x * 256 + threadIdx.x;
    int j = idx & 1023;
    int k = idx >> 10;
    o[(((k >> 3) * 1024) + j) * 8 + (k & 7)] = (_Float16)w[idx];
}

// gx = x @ W_xh + b_xh for t in [t0, t0+256), all 64 batches. Layout [b][tl][1024] f16.
__global__ __launch_bounds__(256) void gx_gemm(
    const float* __restrict__ x,
    const _Float16* __restrict__ Wx,   // packed [32][1024][8]
    const float* __restrict__ b_xh,
    _Float16* __restrict__ gx,
    int t0)
{
    __shared__ _Float16 xl[64 * 280];

    const int tid = threadIdx.x;
    const int nb = blockIdx.x;   // col block 0..15
    const int rb = blockIdx.y;   // row block 0..255

    for (int it = 0; it < 16; ++it) {
        int idx = it * 256 + tid;
        int row = idx >> 6, kq = idx & 63;
        int rlin = rb * 64 + row;
        int b = rlin >> 8, tl = rlin & 255;
        float4 v = *(const float4*)&x[((size_t)b * TT + (t0 + tl)) * DD + kq * 4];
        f16x4 h;
        h[0] = (_Float16)v.x; h[1] = (_Float16)v.y;
        h[2] = (_Float16)v.z; h[3] = (_Float16)v.w;
        *(f16x4*)&xl[row * 280 + kq * 4] = h;
    }
    __syncthreads();

    const int ty = tid >> 4, tx = tid & 15;
    const int col0 = nb * 64 + tx * 4;
    const f16x8* __restrict__ wxp = (const f16x8*)Wx;

    float acc[4][4] = {};
#pragma unroll 2
    for (int kk = 0; kk < 32; ++kk) {
        V8 wv[4], xv[4];
#pragma unroll
        for (int c = 0; c < 4; ++c) wv[c].v = wxp[kk * 1024 + col0 + c];
#pragma unroll
        for (int r = 0; r < 4; ++r)
            xv[r].v = *(const f16x8*)&xl[(ty + 16 * r) * 280 + kk * 8];
#pragma unroll
        for (int r = 0; r < 4; ++r)
#pragma unroll
            for (int c = 0; c < 4; ++c)
#pragma unroll
                for (int q = 0; q < 4; ++q)
                    acc[r][c] = __builtin_amdgcn_fdot2(xv[r].p[q], wv[c].p[q], acc[r][c], false);
    }

    float bb[4];
#pragma unroll
    for (int c = 0; c < 4; ++c) bb[c] = b_xh[col0 + c];

#pragma unroll
    for (int r = 0; r < 4; ++r) {
        int rlin = rb * 64 + ty + 16 * r;
        int b = rlin >> 8, tl = rlin & 255;
        f16x4 o;
#pragma unroll
        for (int c = 0; c < 4; ++c) o[c] = (_Float16)(acc[r][c] + bb[c]);
        *(f16x4*)&gx[((size_t)(b * CHUNK + tl)) * 1024 + col0] = o;
    }
}

// Serial recurrence: 8 blocks x 8 batches, 1024 threads (16 waves).
// Wave w owns dims [16w,16w+16); its W_hh cols {g*256+dim} live in 128 VGPRs/lane
// as MFMA B-fragments. A = h rows [16][256] f16 in LDS (dbuf). One barrier/phase.
__global__ __launch_bounds__(1024, 1) void lstm_serial(
    const float* __restrict__ W_hh,    // [256][1024] f32
    const float* __restrict__ b_hh,    // [1024]
    const _Float16* __restrict__ gx,   // [64][CHUNK][1024]
    float* __restrict__ out,
    float* __restrict__ st,            // h0,h1,c0,c1 each [64][256] f32
    int t0, int nph, int first, int last)
{
    __shared__ _Float16 A[2][16][RS];

    const int tid = threadIdx.x;
    const int blk = blockIdx.x;
    const int w   = tid >> 6;
    const int l   = tid & 63;
    const int l15 = l & 15;
    const int l4  = l >> 4;
    const int dim = w * 16 + l15;      // this lane's h-dim
    const int b0l = 2 * l4;            // local batch for j=0 (lane covers b0l, b0l+1)

    // ---- B fragments: B[k][col], col = g*256+dim, k = kt*32 + l4*8 + e ----
    V8 bf[4][8];
#pragma unroll
    for (int g = 0; g < 4; ++g)
#pragma unroll
        for (int kt = 0; kt < 8; ++kt) {
            f16x8 t;
#pragma unroll
            for (int e = 0; e < 8; ++e)
                t[e] = (_Float16)W_hh[(size_t)(kt * 32 + l4 * 8 + e) * 1024 + g * 256 + dim];
            bf[g][kt].v = t;
        }

    float bh[4];
#pragma unroll
    for (int g = 0; g < 4; ++g) bh[g] = b_hh[g * 256 + dim];

    // ---- state init ----
    float c0[2] = {0.f, 0.f}, c1[2] = {0.f, 0.f};
    {
        float h0i[2] = {0.f, 0.f}, h1i[2] = {0.f, 0.f};
        if (!first) {
#pragma unroll
            for (int j = 0; j < 2; ++j) {
                int gb = blk * PB + b0l + j;
                h0i[j] = st[0 * 16384 + gb * 256 + dim];
                h1i[j] = st[1 * 16384 + gb * 256 + dim];
                c0[j]  = st[2 * 16384 + gb * 256 + dim];
                c1[j]  = st[3 * 16384 + gb * 256 + dim];
            }
        }
#pragma unroll
        for (int j = 0; j < 2; ++j) {
            A[0][(b0l + j) * 2 + 0][dim] = (_Float16)h0i[j];   // h0 row
            A[0][(b0l + j) * 2 + 1][dim] = (_Float16)h1i[j];   // h1 row
        }
    }
    __syncthreads();

    const size_t FIN = (size_t)BB * TT * HH;

    for (int p = 0; p < nph; ++p) {
        const int par = p & 1;
        const bool l0act = (p < CHUNK);
        const bool l1act = !(first && p == 0);

        // gx for this lane's cells (issued early; L2 latency hides under MFMA)
        float gxv[2][4] = {};
        if (l0act) {
#pragma unroll
            for (int j = 0; j < 2; ++j) {
                const _Float16* gp = &gx[((size_t)(blk * PB + b0l + j) * CHUNK + p) * 1024 + dim];
#pragma unroll
                for (int g = 0; g < 4; ++g) gxv[j][g] = (float)gp[g * 256];
            }
        }

        // ---- MFMA: D[row][col] = sum_k A[row][k] * W[k][col] ----
        f32x4 acc[4] = {};
#pragma unroll
        for (int kt = 0; kt < 8; ++kt) {
            V8 af;
            af.v = *(const f16x8*)&A[par][l15][kt * 32 + l4 * 8];
            acc[0] = __builtin_amdgcn_mfma_f32_16x16x32_f16(af.v, bf[0][kt].v, acc[0], 0, 0, 0);
            acc[1] = __builtin_amdgcn_mfma_f32_16x16x32_f16(af.v, bf[1][kt].v, acc[1], 0, 0, 0);
            acc[2] = __builtin_amdgcn_mfma_f32_16x16x32_f16(af.v, bf[2][kt].v, acc[2], 0, 0, 0);
            acc[3] = __builtin_amdgcn_mfma_f32_16x16x32_f16(af.v, bf[3][kt].v, acc[3], 0, 0, 0);
        }

        // ---- update: C row 4*l4+r -> (batch b0l + (r>>1), layer r&1) ----
#pragma unroll
        for (int j = 0; j < 2; ++j) {
            const int gb = blk * PB + b0l + j;
            float h0n = 0.f, h1n = 0.f;
            if (l0act) {
                float gi = acc[0][2 * j] + gxv[j][0] + bh[0];
                float gf = acc[1][2 * j] + gxv[j][1] + bh[1];
                float gg = acc[2][2 * j] + gxv[j][2] + bh[2];
                float go = acc[3][2 * j] + gxv[j][3] + bh[3];
                c0[j] = c0[j] * sigm(gf) + sigm(gi) * tanh_f(gg);
                h0n = sigm(go) * tanh_f(c0[j]);
            }
            if (l1act) {
                float gi = acc[0][2 * j] + acc[0][2 * j + 1] + 2.f * bh[0];
                float gf = acc[1][2 * j] + acc[1][2 * j + 1] + 2.f * bh[1];
                float gg = acc[2][2 * j] + acc[2][2 * j + 1] + 2.f * bh[2];
                float go = acc[3][2 * j] + acc[3][2 * j + 1] + 2.f * bh[3];
                c1[j] = c1[j] * sigm(gf) + sigm(gi) * tanh_f(gg);
                h1n = sigm(go) * tanh_f(c1[j]);
                out[((size_t)gb * TT + (t0 + p - 1)) * HH + dim] = h1n;
            }
            // next-phase A rows
            A[par ^ 1][(b0l + j) * 2 + 0][dim] = (_Float16)h0n;
            A[par ^ 1][(b0l + j) * 2 + 1][dim] = (_Float16)h1n;

            if (last) {
                if (l0act && p == CHUNK - 1) {
                    out[FIN +         gb * 256 + dim] = h0n;     // h_fin[0]
                    out[FIN + 32768 + gb * 256 + dim] = c0[j];   // c_fin[0]
                }
                if (p == nph - 1) {
                    out[FIN + 16384 + gb * 256 + dim] = h1n;     // h_fin[1]
                    out[FIN + 49152 + gb * 256 + dim] = c1[j];   // c_fin[1]
                }
            } else if (p == nph - 1) {
                st[0 * 16384 + gb * 256 + dim] = h0n;
                st[1 * 16384 + gb * 256 + dim] = h1n;
                st[2 * 16384 + gb * 256 + dim] = c0[j];
                st[3 * 16384 + gb * 256 + dim] = c1[j];
            }
        }

        if (p + 1 < nph) __syncthreads();
    }
}

extern "C" void kernel_launch(void* const* d_in, const int* in_sizes, int n_in,
                              void* d_out, int out_size, void* d_ws, size_t ws_size,
                              hipStream_t stream) {
    const float* x    = (const float*)d_in[0];
    const float* W_xh = (const float*)d_in[1];
    const float* b_xh = (const float*)d_in[2];
    const float* W_hh = (const float*)d_in[3];
    const float* b_hh = (const float*)d_in[4];
    float* out = (float*)d_out;

    char* ws = (char*)d_ws;
    _Float16* wxp = (_Float16*)(ws);                    // 512 KB packed W_xh
    float*    st  = (float*)(ws + (512 << 10));         // 256 KB carried state
    _Float16* gx  = (_Float16*)(ws + (768 << 10));      // 33.5 MB gx chunk

    pack_w<<<1024, 256, 0, stream>>>(W_xh, wxp);

    for (int c = 0; c < NCHUNK; ++c) {
        int t0 = c * CHUNK;
        gx_gemm<<<dim3(16, 256), 256, 0, stream>>>(x, wxp, b_xh, gx, t0);
        lstm_serial<<<8, 1024, 0, stream>>>(W_hh, b_hh, gx, out, st,
                                            t0, (c == NCHUNK - 1) ? CHUNK + 1 : CHUNK,
                                            c == 0, c == NCHUNK - 1);
    }
}

// Round 7
// 19016.669 us; speedup vs baseline: 1.2681x; 1.2681x over previous
//
#include <hip/hip_runtime.h>
#include <hip/hip_fp16.h>

#define BB 64
#define TT 2048
#define DD 256
#define HH 256
#define CHUNK 256
#define NCHUNK 8
#define PB 8          // batches per serial block
#define RS 264        // A-row stride (f16): 528 B, 16B-aligned, 2-way bank alias (free)

typedef _Float16 f16x8 __attribute__((ext_vector_type(8)));
typedef _Float16 f16x4 __attribute__((ext_vector_type(4)));
typedef _Float16 h2t   __attribute__((ext_vector_type(2)));
typedef float    f32x4 __attribute__((ext_vector_type(4)));
union V8 { f16x8 v; h2t p[4]; };

__device__ __forceinline__ float sigm(float v){ return __builtin_amdgcn_rcpf(1.f+__expf(-v)); }
__device__ __forceinline__ float tanh_f(float v){ float e=__expf(2.f*v); return 1.f-2.f*__builtin_amdgcn_rcpf(e+1.f); }

// Pack W [256][1024] f32 (k-major) into f16 layout [k/8][1024][8] (for the GEMM)
__global__ void pack_w(const float* __restrict__ w, _Float16* __restrict__ o) {
    int idx = blockIdx.x * 256 + threadIdx.x;
    int j = idx & 1023;
    int k = idx >> 10;
    o[(((k >> 3) * 1024) + j) * 8 + (k & 7)] = (_Float16)w[idx];
}

// gx = x @ W_xh + b_xh for t in [t0, t0+256), all 64 batches.
// Output layout: gx[((b*CHUNK+tl)*256 + dim)*4 + gate] f16  (gate-contiguous per dim)
__global__ __launch_bounds__(256) void gx_gemm(
    const float* __restrict__ x,
    const _Float16* __restrict__ Wx,   // packed [32][1024][8]
    const float* __restrict__ b_xh,
    _Float16* __restrict__ gx,
    int t0)
{
    __shared__ _Float16 xl[64 * 280];

    const int tid = threadIdx.x;
    const int nb = blockIdx.x;   // col block 0..15
    const int rb = blockIdx.y;   // row block 0..255

    for (int it = 0; it < 16; ++it) {
        int idx = it * 256 + tid;
        int row = idx >> 6, kq = idx & 63;
        int rlin = rb * 64 + row;
        int b = rlin >> 8, tl = rlin & 255;
        float4 v = *(const float4*)&x[((size_t)b * TT + (t0 + tl)) * DD + kq * 4];
        f16x4 h;
        h[0] = (_Float16)v.x; h[1] = (_Float16)v.y;
        h[2] = (_Float16)v.z; h[3] = (_Float16)v.w;
        *(f16x4*)&xl[row * 280 + kq * 4] = h;
    }
    __syncthreads();

    const int ty = tid >> 4, tx = tid & 15;
    const int col0 = nb * 64 + tx * 4;
    const int g0 = col0 >> 8, d0 = col0 & 255;
    const f16x8* __restrict__ wxp = (const f16x8*)Wx;

    float acc[4][4] = {};
#pragma unroll 2
    for (int kk = 0; kk < 32; ++kk) {
        V8 wv[4], xv[4];
#pragma unroll
        for (int c = 0; c < 4; ++c) wv[c].v = wxp[kk * 1024 + col0 + c];
#pragma unroll
        for (int r = 0; r < 4; ++r)
            xv[r].v = *(const f16x8*)&xl[(ty + 16 * r) * 280 + kk * 8];
#pragma unroll
        for (int r = 0; r < 4; ++r)
#pragma unroll
            for (int c = 0; c < 4; ++c)
#pragma unroll
                for (int q = 0; q < 4; ++q)
                    acc[r][c] = __builtin_amdgcn_fdot2(xv[r].p[q], wv[c].p[q], acc[r][c], false);
    }

    float bb[4];
#pragma unroll
    for (int c = 0; c < 4; ++c) bb[c] = b_xh[col0 + c];

#pragma unroll
    for (int r = 0; r < 4; ++r) {
        int rlin = rb * 64 + ty + 16 * r;
        int b = rlin >> 8, tl = rlin & 255;
#pragma unroll
        for (int c = 0; c < 4; ++c)
            gx[((size_t)(b * CHUNK + tl) * 256 + (d0 + c)) * 4 + g0] =
                (_Float16)(acc[r][c] + bb[c]);
    }
}

// ---- macro machinery: 32 NAMED weight fragments (nothing indexable -> no scratch) ----
#define FOR_KT(M) M(0) M(1) M(2) M(3) M(4) M(5) M(6) M(7)

#define DECL_BF(kt) f16x8 bf0_##kt, bf1_##kt, bf2_##kt, bf3_##kt;

#define LOAD_BF1(g, kt, dst) { \
    f16x8 t_; \
    _Pragma("unroll") \
    for (int e = 0; e < 8; ++e) \
        t_[e] = (_Float16)W_hh[(size_t)((kt) * 32 + l4 * 8 + e) * 1024 + (g) * 256 + dim]; \
    dst = t_; }

#define LOAD_BF(kt) \
    LOAD_BF1(0, kt, bf0_##kt) LOAD_BF1(1, kt, bf1_##kt) \
    LOAD_BF1(2, kt, bf2_##kt) LOAD_BF1(3, kt, bf3_##kt)

#define MFMA_STEP(kt) { \
    f16x8 af_ = *(const f16x8*)&Abase[l15 * RS + (kt) * 32 + l4 * 8]; \
    acc0 = __builtin_amdgcn_mfma_f32_16x16x32_f16(af_, bf0_##kt, acc0, 0, 0, 0); \
    acc1 = __builtin_amdgcn_mfma_f32_16x16x32_f16(af_, bf1_##kt, acc1, 0, 0, 0); \
    acc2 = __builtin_amdgcn_mfma_f32_16x16x32_f16(af_, bf2_##kt, acc2, 0, 0, 0); \
    acc3 = __builtin_amdgcn_mfma_f32_16x16x32_f16(af_, bf3_##kt, acc3, 0, 0, 0); }

// Serial recurrence: 8 blocks x 8 batches, 1024 threads (16 waves).
// Wave w owns dims [16w,16w+16); W_hh cols {g*256+dim} in 128 named VGPRs/lane.
__global__ __launch_bounds__(1024, 1) void lstm_serial(
    const float* __restrict__ W_hh,    // [256][1024] f32
    const float* __restrict__ b_hh,    // [1024]
    const _Float16* __restrict__ gx,   // [(b*CHUNK+tl)*256 + dim]*4 + gate
    float* __restrict__ out,
    float* __restrict__ st,            // h0,h1,c0,c1 each [64][256] f32
    int t0, int nph, int first, int last)
{
    __shared__ _Float16 A[2][16][RS];

    const int tid = threadIdx.x;
    const int blk = blockIdx.x;
    const int w   = tid >> 6;
    const int l   = tid & 63;
    const int l15 = l & 15;
    const int l4  = l >> 4;
    const int dim = w * 16 + l15;      // this lane's h-dim
    const int b0l = 2 * l4;            // local batch for j=0 (lane covers b0l, b0l+1)

    FOR_KT(DECL_BF)
    FOR_KT(LOAD_BF)

    float bh[4];
#pragma unroll
    for (int g = 0; g < 4; ++g) bh[g] = b_hh[g * 256 + dim];

    // ---- state init ----
    float c0[2] = {0.f, 0.f}, c1[2] = {0.f, 0.f};
    {
        float h0i[2] = {0.f, 0.f}, h1i[2] = {0.f, 0.f};
        if (!first) {
#pragma unroll
            for (int j = 0; j < 2; ++j) {
                int gb = blk * PB + b0l + j;
                h0i[j] = st[0 * 16384 + gb * 256 + dim];
                h1i[j] = st[1 * 16384 + gb * 256 + dim];
                c0[j]  = st[2 * 16384 + gb * 256 + dim];
                c1[j]  = st[3 * 16384 + gb * 256 + dim];
            }
        }
#pragma unroll
        for (int j = 0; j < 2; ++j) {
            A[0][(b0l + j) * 2 + 0][dim] = (_Float16)h0i[j];   // h0 row
            A[0][(b0l + j) * 2 + 1][dim] = (_Float16)h1i[j];   // h1 row
        }
    }
    __syncthreads();

    const size_t FIN = (size_t)BB * TT * HH;

    for (int p = 0; p < nph; ++p) {
        const int par = p & 1;
        const bool l0act = (p < CHUNK);
        const bool l1act = !(first && p == 0);
        const _Float16* Abase = &A[par][0][0];

        // gx: one coalesced 8B load per (lane, batch)
        f16x4 gv0 = {}, gv1 = {};
        if (l0act) {
            gv0 = *(const f16x4*)&gx[((size_t)((blk * PB + b0l + 0) * CHUNK + p) * 256 + dim) * 4];
            gv1 = *(const f16x4*)&gx[((size_t)((blk * PB + b0l + 1) * CHUNK + p) * 256 + dim) * 4];
        }

        // ---- MFMA: D[row][col] = sum_k A[row][k] * W[k][col] ----
        f32x4 acc0 = {}, acc1 = {}, acc2 = {}, acc3 = {};
        FOR_KT(MFMA_STEP)

        // ---- update: C row 4*l4+2j+l -> (batch b0l+j, layer l) ----
#pragma unroll
        for (int j = 0; j < 2; ++j) {
            const int gb = blk * PB + b0l + j;
            const f16x4 gv = j ? gv1 : gv0;
            float h0n = 0.f, h1n = 0.f;
            if (l0act) {
                float gi = acc0[2 * j] + (float)gv[0] + bh[0];
                float gf = acc1[2 * j] + (float)gv[1] + bh[1];
                float gg = acc2[2 * j] + (float)gv[2] + bh[2];
                float go = acc3[2 * j] + (float)gv[3] + bh[3];
                c0[j] = c0[j] * sigm(gf) + sigm(gi) * tanh_f(gg);
                h0n = sigm(go) * tanh_f(c0[j]);
            }
            if (l1act) {
                float gi = acc0[2 * j] + acc0[2 * j + 1] + 2.f * bh[0];
                float gf = acc1[2 * j] + acc1[2 * j + 1] + 2.f * bh[1];
                float gg = acc2[2 * j] + acc2[2 * j + 1] + 2.f * bh[2];
                float go = acc3[2 * j] + acc3[2 * j + 1] + 2.f * bh[3];
                c1[j] = c1[j] * sigm(gf) + sigm(gi) * tanh_f(gg);
                h1n = sigm(go) * tanh_f(c1[j]);
                out[((size_t)gb * TT + (t0 + p - 1)) * HH + dim] = h1n;
            }
            // next-phase A rows
            A[par ^ 1][(b0l + j) * 2 + 0][dim] = (_Float16)h0n;
            A[par ^ 1][(b0l + j) * 2 + 1][dim] = (_Float16)h1n;

            if (last) {
                if (l0act && p == CHUNK - 1) {
                    out[FIN +         gb * 256 + dim] = h0n;     // h_fin[0]
                    out[FIN + 32768 + gb * 256 + dim] = c0[j];   // c_fin[0]
                }
                if (p == nph - 1) {
                    out[FIN + 16384 + gb * 256 + dim] = h1n;     // h_fin[1]
                    out[FIN + 49152 + gb * 256 + dim] = c1[j];   // c_fin[1]
                }
            } else if (p == nph - 1) {
                st[0 * 16384 + gb * 256 + dim] = h0n;
                st[1 * 16384 + gb * 256 + dim] = h1n;
                st[2 * 16384 + gb * 256 + dim] = c0[j];
                st[3 * 16384 + gb * 256 + dim] = c1[j];
            }
        }

        if (p + 1 < nph) __syncthreads();
    }
}

extern "C" void kernel_launch(void* const* d_in, const int* in_sizes, int n_in,
                              void* d_out, int out_size, void* d_ws, size_t ws_size,
                              hipStream_t stream) {
    const float* x    = (const float*)d_in[0];
    const float* W_xh = (const float*)d_in[1];
    const float* b_xh = (const float*)d_in[2];
    const float* W_hh = (const float*)d_in[3];
    const float* b_hh = (const float*)d_in[4];
    float* out = (float*)d_out;

    char* ws = (char*)d_ws;
    _Float16* wxp = (_Float16*)(ws);                    // 512 KB packed W_xh
    float*    st  = (float*)(ws + (512 << 10));         // 256 KB carried state
    _Float16* gx  = (_Float16*)(ws + (768 << 10));      // 33.5 MB gx chunk

    pack_w<<<1024, 256, 0, stream>>>(W_xh, wxp);

    for (int c = 0; c < NCHUNK; ++c) {
        int t0 = c * CHUNK;
        gx_gemm<<<dim3(16, 256), 256, 0, stream>>>(x, wxp, b_xh, gx, t0);
        lstm_serial<<<8, 1024, 0, stream>>>(W_hh, b_hh, gx, out, st,
                                            t0, (c == NCHUNK - 1) ? CHUNK + 1 : CHUNK,
                                            c == 0, c == NCHUNK - 1);
    }
}

// Round 8
// 8679.964 us; speedup vs baseline: 2.7783x; 2.1909x over previous
//
#include <hip/hip_runtime.h>
#include <hip/hip_fp16.h>

#define BB 64
#define TT 2048
#define DD 256
#define HH 256
#define CHUNK 256
#define NCHUNK 8
#define PB 8          // batches per serial block
#define RS 264        // A-row stride (f16)

typedef _Float16 f16x8 __attribute__((ext_vector_type(8)));
typedef _Float16 f16x4 __attribute__((ext_vector_type(4)));
typedef _Float16 h2t   __attribute__((ext_vector_type(2)));
typedef float    f32x4 __attribute__((ext_vector_type(4)));
union V8 { f16x8 v; h2t p[4]; };

__device__ __forceinline__ float sigm(float v){ return __builtin_amdgcn_rcpf(1.f+__expf(-v)); }
__device__ __forceinline__ float tanh_f(float v){ float e=__expf(2.f*v); return 1.f-2.f*__builtin_amdgcn_rcpf(e+1.f); }

// Pack W [256][1024] f32 (k-major) into f16 layout [k/8][1024][8] (for the GEMM)
__global__ void pack_w(const float* __restrict__ w, _Float16* __restrict__ o) {
    int idx = blockIdx.x * 256 + threadIdx.x;
    int j = idx & 1023;
    int k = idx >> 10;
    o[(((k >> 3) * 1024) + j) * 8 + (k & 7)] = (_Float16)w[idx];
}

// gx = x @ W_xh + (b_xh + b_hh) for t in [t0, t0+256), all 64 batches.
// Layout: gx[((b*CHUNK+tl)*256 + dim)*4 + gate] f16
__global__ __launch_bounds__(256) void gx_gemm(
    const float* __restrict__ x,
    const _Float16* __restrict__ Wx,   // packed [32][1024][8]
    const float* __restrict__ b_xh,
    const float* __restrict__ b_hh,
    _Float16* __restrict__ gx,
    int t0)
{
    __shared__ _Float16 xl[64 * 280];

    const int tid = threadIdx.x;
    const int nb = blockIdx.x;   // col block 0..15
    const int rb = blockIdx.y;   // row block 0..255

    for (int it = 0; it < 16; ++it) {
        int idx = it * 256 + tid;
        int row = idx >> 6, kq = idx & 63;
        int rlin = rb * 64 + row;
        int b = rlin >> 8, tl = rlin & 255;
        float4 v = *(const float4*)&x[((size_t)b * TT + (t0 + tl)) * DD + kq * 4];
        f16x4 h;
        h[0] = (_Float16)v.x; h[1] = (_Float16)v.y;
        h[2] = (_Float16)v.z; h[3] = (_Float16)v.w;
        *(f16x4*)&xl[row * 280 + kq * 4] = h;
    }
    __syncthreads();

    const int ty = tid >> 4, tx = tid & 15;
    const int col0 = nb * 64 + tx * 4;
    const int g0 = col0 >> 8, d0 = col0 & 255;
    const f16x8* __restrict__ wxp = (const f16x8*)Wx;

    float acc[4][4] = {};
#pragma unroll 2
    for (int kk = 0; kk < 32; ++kk) {
        V8 wv[4], xv[4];
#pragma unroll
        for (int c = 0; c < 4; ++c) wv[c].v = wxp[kk * 1024 + col0 + c];
#pragma unroll
        for (int r = 0; r < 4; ++r)
            xv[r].v = *(const f16x8*)&xl[(ty + 16 * r) * 280 + kk * 8];
#pragma unroll
        for (int r = 0; r < 4; ++r)
#pragma unroll
            for (int c = 0; c < 4; ++c)
#pragma unroll
                for (int q = 0; q < 4; ++q)
                    acc[r][c] = __builtin_amdgcn_fdot2(xv[r].p[q], wv[c].p[q], acc[r][c], false);
    }

    float bb[4];
#pragma unroll
    for (int c = 0; c < 4; ++c) bb[c] = b_xh[col0 + c] + b_hh[col0 + c];

#pragma unroll
    for (int r = 0; r < 4; ++r) {
        int rlin = rb * 64 + ty + 16 * r;
        int b = rlin >> 8, tl = rlin & 255;
#pragma unroll
        for (int c = 0; c < 4; ++c)
            gx[((size_t)(b * CHUNK + tl) * 256 + (d0 + c)) * 4 + g0] =
                (_Float16)(acc[r][c] + bb[c]);
    }
}

// ================= serial kernel macros =================
#define FOR_GDH(M) M(0,0) M(0,1) M(1,0) M(1,1) M(2,0) M(2,1) M(3,0) M(3,1)

#define DECLW(g,dh) f16x8 wf_##g##_##dh##_0, wf_##g##_##dh##_1, wf_##g##_##dh##_2, \
                          wf_##g##_##dh##_3, wf_##g##_##dh##_4, wf_##g##_##dh##_5;

#define LOADW1(g,dh,kt) { f16x8 t_; \
    _Pragma("unroll") \
    for (int e = 0; e < 8; ++e) \
        t_[e] = (_Float16)W_hh[(size_t)((kt)*32 + l4*8 + e)*1024 + (g)*256 + wbase + (dh)*16 + l15]; \
    wf_##g##_##dh##_##kt = t_; }

#define LOADW(g,dh) LOADW1(g,dh,0) LOADW1(g,dh,1) LOADW1(g,dh,2) \
                    LOADW1(g,dh,3) LOADW1(g,dh,4) LOADW1(g,dh,5)

#define KTR(kt,dh) { f16x8 af_ = *(const f16x8*)&Ab[(kt)*32 + l4*8]; \
    ac0_ = __builtin_amdgcn_mfma_f32_16x16x32_f16(af_, wf_0_##dh##_##kt, ac0_, 0,0,0); \
    ac1_ = __builtin_amdgcn_mfma_f32_16x16x32_f16(af_, wf_1_##dh##_##kt, ac1_, 0,0,0); \
    ac2_ = __builtin_amdgcn_mfma_f32_16x16x32_f16(af_, wf_2_##dh##_##kt, ac2_, 0,0,0); \
    ac3_ = __builtin_amdgcn_mfma_f32_16x16x32_f16(af_, wf_3_##dh##_##kt, ac3_, 0,0,0); }

#define BLD(g,dh,kt) (*(const f16x8*)&Wl[(size_t)((((kt)-6)*4 + l4)*1024 + (g)*256 + wbase + (dh)*16 + l15)*8])

#define KTL(kt,dh) { f16x8 af_ = *(const f16x8*)&Ab[(kt)*32 + l4*8]; \
    ac0_ = __builtin_amdgcn_mfma_f32_16x16x32_f16(af_, BLD(0,dh,kt), ac0_, 0,0,0); \
    ac1_ = __builtin_amdgcn_mfma_f32_16x16x32_f16(af_, BLD(1,dh,kt), ac1_, 0,0,0); \
    ac2_ = __builtin_amdgcn_mfma_f32_16x16x32_f16(af_, BLD(2,dh,kt), ac2_, 0,0,0); \
    ac3_ = __builtin_amdgcn_mfma_f32_16x16x32_f16(af_, BLD(3,dh,kt), ac3_, 0,0,0); }

#define UPD(j,dh) { \
    const int gb_ = blk*PB + 2*l4 + (j); \
    const int d_  = wbase + (dh)*16 + l15; \
    float h0n_ = 0.f, h1n_ = 0.f; \
    if (l0act) { \
        float gi_ = ac0_[2*(j)] + (float)gv##j##_[0]; \
        float gf_ = ac1_[2*(j)] + (float)gv##j##_[1]; \
        float gg_ = ac2_[2*(j)] + (float)gv##j##_[2]; \
        float go_ = ac3_[2*(j)] + (float)gv##j##_[3]; \
        c0s_##dh[j] = c0s_##dh[j]*sigm(gf_) + sigm(gi_)*tanh_f(gg_); \
        h0n_ = sigm(go_)*tanh_f(c0s_##dh[j]); \
    } \
    if (l1act) { \
        float gi_ = ac0_[2*(j)] + ac0_[2*(j)+1] + bh2_##dh##_0; \
        float gf_ = ac1_[2*(j)] + ac1_[2*(j)+1] + bh2_##dh##_1; \
        float gg_ = ac2_[2*(j)] + ac2_[2*(j)+1] + bh2_##dh##_2; \
        float go_ = ac3_[2*(j)] + ac3_[2*(j)+1] + bh2_##dh##_3; \
        c1s_##dh[j] = c1s_##dh[j]*sigm(gf_) + sigm(gi_)*tanh_f(gg_); \
        h1n_ = sigm(go_)*tanh_f(c1s_##dh[j]); \
        out[((size_t)gb_*TT + (t0 + p - 1))*HH + d_] = h1n_; \
    } \
    A[parx][(2*l4+(j))*2 + 0][d_] = (_Float16)h0n_; \
    A[parx][(2*l4+(j))*2 + 1][d_] = (_Float16)h1n_; \
    if (last) { \
        if (l0act && p == CHUNK-1) { out[FIN + gb_*256 + d_] = h0n_; out[FIN + 32768 + gb_*256 + d_] = c0s_##dh[j]; } \
        if (p == nph-1) { out[FIN + 16384 + gb_*256 + d_] = h1n_; out[FIN + 49152 + gb_*256 + d_] = c1s_##dh[j]; } \
    } else if (p == nph-1) { \
        st[gb_*256 + d_] = h0n_; st[16384 + gb_*256 + d_] = h1n_; \
        st[32768 + gb_*256 + d_] = c0s_##dh[j]; st[49152 + gb_*256 + d_] = c1s_##dh[j]; } }

#define HALF(dh) { \
    f16x4 gv0_ = {}, gv1_ = {}; \
    if (l0act) { \
        gv0_ = *(const f16x4*)&gx[((size_t)((blk*PB + 2*l4 + 0)*CHUNK + p)*256 + wbase + (dh)*16 + l15)*4]; \
        gv1_ = *(const f16x4*)&gx[((size_t)((blk*PB + 2*l4 + 1)*CHUNK + p)*256 + wbase + (dh)*16 + l15)*4]; \
    } \
    f32x4 ac0_ = {}, ac1_ = {}, ac2_ = {}, ac3_ = {}; \
    KTR(0,dh) KTR(1,dh) KTR(2,dh) KTR(3,dh) KTR(4,dh) KTR(5,dh) \
    KTL(6,dh) KTL(7,dh) \
    UPD(0,dh) UPD(1,dh) }

#define STINIT(j,dh) { \
    int gb_ = blk*PB + 2*l4 + (j); \
    int d_  = wbase + (dh)*16 + l15; \
    float h0i_ = 0.f, h1i_ = 0.f; \
    if (!first) { \
        h0i_ = st[gb_*256 + d_]; h1i_ = st[16384 + gb_*256 + d_]; \
        c0s_##dh[j] = st[32768 + gb_*256 + d_]; c1s_##dh[j] = st[49152 + gb_*256 + d_]; \
    } \
    A[0][(2*l4+(j))*2 + 0][d_] = (_Float16)h0i_; \
    A[0][(2*l4+(j))*2 + 1][d_] = (_Float16)h1i_; }

// Serial recurrence: 8 blocks x 8 batches, 512 threads (8 waves, 2/SIMD, 256 VGPR cap).
// Wave w owns dims [32w,32w+32). W_hh k in [0,192) in 192 named VGPRs/wave;
// k in [192,256) in 128 KB LDS. All weights CU-resident.
__global__ __launch_bounds__(512, 2) void lstm_serial(
    const float* __restrict__ W_hh,    // [256][1024] f32
    const float* __restrict__ b_hh,    // [1024]
    const _Float16* __restrict__ gx,   // [(b*CHUNK+tl)*256 + dim]*4 + gate (incl. b_xh+b_hh)
    float* __restrict__ out,
    float* __restrict__ st,            // h0,h1,c0,c1 each [64][256] f32
    int t0, int nph, int first, int last)
{
    __shared__ _Float16 A[2][16][RS];            // 16.9 KB
    __shared__ _Float16 Wl[8 * 1024 * 8];        // 128 KB: [(kt-6)*4+ch][col][8]

    const int tid = threadIdx.x;
    const int blk = blockIdx.x;
    const int l   = tid & 63;
    const int l15 = l & 15;
    const int l4  = l >> 4;
    const int wbase = (tid >> 6) * 32;

    // ---- stage LDS weights: k in [192,256) ----
    for (int v = tid; v < 8192; v += 512) {
        int blk8 = v >> 10, col = v & 1023;
        f16x8 t;
#pragma unroll
        for (int e = 0; e < 8; ++e)
            t[e] = (_Float16)W_hh[(size_t)(192 + blk8 * 8 + e) * 1024 + col];
        *(f16x8*)&Wl[(size_t)v * 8] = t;
    }

    // ---- weight registers: k in [0,192), 48 named f16x8 ----
    FOR_GDH(DECLW)
    FOR_GDH(LOADW)

    // ---- 2*b_hh for layer-1 gates (8 named floats) ----
    float bh2_0_0 = 2.f*b_hh[0*256 + wbase + l15],      bh2_0_1 = 2.f*b_hh[1*256 + wbase + l15];
    float bh2_0_2 = 2.f*b_hh[2*256 + wbase + l15],      bh2_0_3 = 2.f*b_hh[3*256 + wbase + l15];
    float bh2_1_0 = 2.f*b_hh[0*256 + wbase + 16 + l15], bh2_1_1 = 2.f*b_hh[1*256 + wbase + 16 + l15];
    float bh2_1_2 = 2.f*b_hh[2*256 + wbase + 16 + l15], bh2_1_3 = 2.f*b_hh[3*256 + wbase + 16 + l15];

    // ---- state ----
    float c0s_0[2] = {0.f,0.f}, c0s_1[2] = {0.f,0.f};
    float c1s_0[2] = {0.f,0.f}, c1s_1[2] = {0.f,0.f};
    STINIT(0,0) STINIT(0,1) STINIT(1,0) STINIT(1,1)
    __syncthreads();

    const size_t FIN = (size_t)BB * TT * HH;

    for (int p = 0; p < nph; ++p) {
        const int par = p & 1, parx = par ^ 1;
        const bool l0act = (p < CHUNK);
        const bool l1act = !(first && p == 0);
        const _Float16* Ab = &A[par][l15][0];

        HALF(0)
        HALF(1)

        __syncthreads();
    }
}

extern "C" void kernel_launch(void* const* d_in, const int* in_sizes, int n_in,
                              void* d_out, int out_size, void* d_ws, size_t ws_size,
                              hipStream_t stream) {
    const float* x    = (const float*)d_in[0];
    const float* W_xh = (const float*)d_in[1];
    const float* b_xh = (const float*)d_in[2];
    const float* W_hh = (const float*)d_in[3];
    const float* b_hh = (const float*)d_in[4];
    float* out = (float*)d_out;

    char* ws = (char*)d_ws;
    _Float16* wxp = (_Float16*)(ws);                    // 512 KB packed W_xh
    float*    st  = (float*)(ws + (512 << 10));         // 256 KB carried state
    _Float16* gx  = (_Float16*)(ws + (768 << 10));      // 33.5 MB gx chunk

    pack_w<<<1024, 256, 0, stream>>>(W_xh, wxp);

    for (int c = 0; c < NCHUNK; ++c) {
        int t0 = c * CHUNK;
        gx_gemm<<<dim3(16, 256), 256, 0, stream>>>(x, wxp, b_xh, b_hh, gx, t0);
        lstm_serial<<<8, 512, 0, stream>>>(W_hh, b_hh, gx, out, st,
                                           t0, (c == NCHUNK - 1) ? CHUNK + 1 : CHUNK,
                                           c == 0, c == NCHUNK - 1);
    }
}